// Round 1
// 807.955 us; speedup vs baseline: 1.0409x; 1.0409x over previous
//
#include <hip/hip_runtime.h>

typedef unsigned short u16;
typedef unsigned int u32;

using short8 = __attribute__((ext_vector_type(8))) short;
using f32x4  = __attribute__((ext_vector_type(4))) float;

constexpr int kB = 2, kT = 2048, kD = 2048, kH = 16, kK = 128, kV = 128;
constexpr int kM  = kB * kT;   // 4096 tokens
constexpr int kHK = kH * kK;   // 2048
constexpr int kHV = kH * kV;   // 2048
constexpr int CC  = 16;        // scan chunk length
constexpr int NCH = kT / CC;   // 128 chunks

// ---------------- workspace layout (bytes). Overlays are deliberate. -------
// timeline: casts -> gemms(qkv,fgb,graw,gateb) -> convprep -> p1 -> p2 -> postk -> out-gemm
constexpr size_t OFF_XB    = 0;          // bf16 x [4096][2048] (dead after gemms)
constexpr size_t OFF_WQKV  = 16777216;   // bf16 [6144][2048] = Wq|Wk|Wv stacked (dead after qkv gemm)
constexpr size_t OFF_QC    = 0;          // f32 qc [32][2048][128] 33.5MB (convprep out; over XB+Wq+Wk)
constexpr size_t OFF_YF    = 0;          // f32 y [32][2048][128] (p2 out; qc dead after p1)
constexpr size_t OFF_WF1B  = 41943040;   // bf16 Wf1 [128][2048]
constexpr size_t OFF_WG1B  = 42467328;   // bf16 Wg1
constexpr size_t OFF_WBP   = 42991616;   // bf16 Wb padded [128][2048]  (F1|G1|BP contiguous = N=384)
constexpr size_t OFF_WF2B  = 43515904;   // bf16 Wf2
constexpr size_t OFF_WG2B  = 44040192;   // bf16 Wg2
constexpr size_t OFF_FGB   = 44564480;   // bf16 fgb [4096][384] (f1|g1|braw)
constexpr size_t OFF_QKVR  = 48758784;   // bf16 qkvraw [4096][6144] 50.3MB (dead after convprep)
constexpr size_t OFF_QHB   = 48758784;   // bf16 qhat [32][2048][128] (p1 out, over qkvraw)
constexpr size_t OFF_KBB   = 65536000;   // bf16 kbar TRANSPOSED [32][128ch][128k][16t]
constexpr size_t OFF_KHB   = 82313216;   // bf16 khat
constexpr size_t OFF_YGB   = 82313216;   // bf16 y-gated (postk out, khb dead by then)
constexpr size_t OFF_GRAW  = 99090432;   // bf16 g_raw [4096][2048] (dead after convprep)
constexpr size_t OFF_LAM   = 99090432;   // f32 lam  [32][128][128] (p1 out, over graw)
constexpr size_t OFF_WINV  = 101187584;  // f32 winv [32][128][256]
constexpr size_t OFF_MM    = 105381888;  // f32 M    [32][128][256]
constexpr size_t OFF_GATEB = 115867648;  // bf16 gate [4096][2048]
constexpr size_t OFF_WOUTB = 132644864;  // bf16 Wout
constexpr size_t OFF_KC    = 141033472;  // f32 kc
constexpr size_t OFF_VT    = 174587904;  // f32 v transposed [bh*8+vs][t][16]
constexpr size_t OFF_GK    = 208142336;  // f32 log-decay g
constexpr size_t OFF_BETA  = 241696768;  // f32 beta [32][2048]
// total 241958912 bytes (~231 MB), unchanged

// ---------------- small helpers ----------------
__device__ __forceinline__ u16 f2bf(float f) {
  union { float f; u32 u; } a; a.f = f;
  u32 u = a.u;
  u += 0x7fffu + ((u >> 16) & 1u);   // round-to-nearest-even
  return (u16)(u >> 16);
}
__device__ __forceinline__ float bflo(u32 u) {
  union { u32 u; float f; } a; a.u = u << 16; return a.f;
}
__device__ __forceinline__ float bfhi(u32 u) {
  union { u32 u; float f; } a; a.u = u & 0xffff0000u; return a.f;
}
__device__ __forceinline__ float sigmoidf(float x) { return 1.0f / (1.0f + expf(-x)); }

#define GL_AS1 __attribute__((address_space(1)))
#define GL_AS3 __attribute__((address_space(3)))
__device__ __forceinline__ void async_lds16(const void* g, void* l) {
  __builtin_amdgcn_global_load_lds((GL_AS1 u32*)(size_t)g,
                                   (GL_AS3 u32*)(u32)(size_t)l, 16, 0, 0);
}

// ---------------- fused cast of all f32->bf16 weights/x --------------------
__global__ __launch_bounds__(256) void cast_all(
    const float* __restrict__ x, const float* __restrict__ Wq,
    const float* __restrict__ Wk, const float* __restrict__ Wv,
    const float* __restrict__ Wout, const float* __restrict__ Wf1,
    const float* __restrict__ Wg1, const float* __restrict__ Wf2,
    const float* __restrict__ Wg2,
    u16* __restrict__ xb, u16* __restrict__ wqkv, u16* __restrict__ woutb,
    u16* __restrict__ wf1b, u16* __restrict__ wg1b, u16* __restrict__ wf2b,
    u16* __restrict__ wg2b) {
  long qi = (long)blockIdx.x * 256 + threadIdx.x;   // float4 index
  const float* src; u16* dst; long off;
  if (qi < 2097152)      { src = x;    dst = xb;             off = qi; }
  else if (qi < 3145728) { src = Wq;   dst = wqkv;           off = qi - 2097152; }
  else if (qi < 4194304) { src = Wk;   dst = wqkv + 4194304; off = qi - 3145728; }
  else if (qi < 5242880) { src = Wv;   dst = wqkv + 8388608; off = qi - 4194304; }
  else if (qi < 6291456) { src = Wout; dst = woutb;          off = qi - 5242880; }
  else if (qi < 6356992) { src = Wf1;  dst = wf1b;           off = qi - 6291456; }
  else if (qi < 6422528) { src = Wg1;  dst = wg1b;           off = qi - 6356992; }
  else if (qi < 6488064) { src = Wf2;  dst = wf2b;           off = qi - 6422528; }
  else                   { src = Wg2;  dst = wg2b;           off = qi - 6488064; }
  long i = off * 4;
  float4 v = *(const float4*)(src + i);
  uint2 st;
  st.x = (u32)f2bf(v.x) | ((u32)f2bf(v.y) << 16);
  st.y = (u32)f2bf(v.z) | ((u32)f2bf(v.w) << 16);
  *(uint2*)(dst + i) = st;
}

// Wb [16,2048] f32 -> [128,2048] bf16 zero-padded
__global__ __launch_bounds__(256) void pad_wb(const float* __restrict__ Wb,
                                              u16* __restrict__ out) {
  int i = (blockIdx.x * 256 + threadIdx.x) * 4;  // < 262144
  int row = i >> 11;
  uint2 st; st.x = 0; st.y = 0;
  if (row < 16) {
    float4 v = *(const float4*)(Wb + i);
    st.x = (u32)f2bf(v.x) | ((u32)f2bf(v.y) << 16);
    st.y = (u32)f2bf(v.z) | ((u32)f2bf(v.w) << 16);
  }
  *(uint2*)(out + i) = st;
}

// ---------------- bf16 MFMA GEMM:  C[m,n] = sum_k A[m,k] * B[n,k] ----------
template <bool BF16OUT>
__global__ __launch_bounds__(256) void gemm_bt(const u16* __restrict__ A,
                                               const u16* __restrict__ B,
                                               void* __restrict__ Cout,
                                               int lda, int ldb, int ldc, int K) {
  __shared__ u16 As[128 * 32];
  __shared__ u16 Bs[128 * 32];
  const int tid  = threadIdx.x;
  const int lane = tid & 63;
  const int wave = tid >> 6;
  const int wm = (wave >> 1) * 64;
  const int wn = (wave & 1) * 64;
  const long row0 = (long)blockIdx.x * 128;
  const long col0 = (long)blockIdx.y * 128;
  const int srow = tid >> 2;
  const int scol = (tid & 3) * 8;
  const u16* aptr = A + (row0 + srow) * (size_t)lda + scol;
  const u16* bptr = B + (col0 + srow) * (size_t)ldb + scol;
  u16* asd  = &As[tid * 8];
  u16* asd2 = &As[2048 + tid * 8];
  u16* bsd  = &Bs[tid * 8];
  u16* bsd2 = &Bs[2048 + tid * 8];
  const int mrow = lane & 15;
  const int kq = (lane >> 4) * 8;
  f32x4 acc[4][4] = {};
  for (int k0 = 0; k0 < K; k0 += 32) {
    async_lds16(aptr, asd);
    async_lds16(aptr + (size_t)64 * lda, asd2);
    async_lds16(bptr, bsd);
    async_lds16(bptr + (size_t)64 * ldb, bsd2);
    aptr += 32; bptr += 32;
    __syncthreads();
    short8 af[4], bfr[4];
#pragma unroll
    for (int i = 0; i < 4; ++i)
      af[i] = *(const short8*)(&As[(wm + i * 16 + mrow) * 32 + kq]);
#pragma unroll
    for (int j = 0; j < 4; ++j)
      bfr[j] = *(const short8*)(&Bs[(wn + j * 16 + mrow) * 32 + kq]);
#pragma unroll
    for (int i = 0; i < 4; ++i)
#pragma unroll
      for (int j = 0; j < 4; ++j)
        acc[i][j] = __builtin_amdgcn_mfma_f32_16x16x32_bf16(af[i], bfr[j], acc[i][j], 0, 0, 0);
    __syncthreads();
  }
  const int cn = lane & 15;
  const int rq = (lane >> 4) * 4;
#pragma unroll
  for (int i = 0; i < 4; ++i)
#pragma unroll
    for (int j = 0; j < 4; ++j) {
      size_t r = (size_t)(row0 + wm + i * 16 + rq);
      size_t c = (size_t)(col0 + wn + j * 16 + cn);
#pragma unroll
      for (int rr = 0; rr < 4; ++rr) {
        if constexpr (BF16OUT)
          ((u16*)Cout)[(r + rr) * ldc + c] = f2bf(acc[i][j][rr]);
        else
          ((float*)Cout)[(r + rr) * ldc + c] = acc[i][j][rr];
      }
    }
}

// ---------------- conv(4-tap causal) + silu + l2norm + g + beta ------------
__global__ __launch_bounds__(256) void convprep(
    const u16* __restrict__ qkv, const u16* __restrict__ graw,
    const u16* __restrict__ fgb,
    const float* __restrict__ qcw, const float* __restrict__ kcw,
    const float* __restrict__ vcw, const float* __restrict__ A_log,
    const float* __restrict__ dt_bias,
    float* __restrict__ qc, float* __restrict__ kc, float* __restrict__ vt,
    float* __restrict__ gdec, float* __restrict__ beta) {
  const int wid  = blockIdx.x * 4 + (threadIdx.x >> 6);
  const int lane = threadIdx.x & 63;
  const int h  = wid & 15;
  const int bt = wid >> 4;        // b*T + t
  const int t  = bt & (kT - 1);
  const int b  = bt >> 11;
  const int c0 = lane * 2;
  const size_t colofs = (size_t)h * kK + c0;
  const size_t rowb = (size_t)bt * 6144 + colofs;
  const float* wq = qcw + colofs * 4;
  const float* wk = kcw + colofs * 4;
  const float* wv = vcw + colofs * 4;
  float qa0 = 0, qa1 = 0, ka0 = 0, ka1 = 0, va0 = 0, va1 = 0;
#pragma unroll
  for (int i = 0; i < 4; ++i) {
    int tt = t - 3 + i;
    if (tt >= 0) {
      size_t ro = rowb - (size_t)(3 - i) * 6144;
      u32 uq = *(const u32*)(qkv + ro);
      u32 uk = *(const u32*)(qkv + ro + 2048);
      u32 uv = *(const u32*)(qkv + ro + 4096);
      qa0 += bflo(uq) * wq[i];  qa1 += bfhi(uq) * wq[4 + i];
      ka0 += bflo(uk) * wk[i];  ka1 += bfhi(uk) * wk[4 + i];
      va0 += bflo(uv) * wv[i];  va1 += bfhi(uv) * wv[4 + i];
    }
  }
  qa0 *= sigmoidf(qa0); qa1 *= sigmoidf(qa1);
  ka0 *= sigmoidf(ka0); ka1 *= sigmoidf(ka1);
  va0 *= sigmoidf(va0); va1 *= sigmoidf(va1);
  float sq = qa0 * qa0 + qa1 * qa1;
  float sk = ka0 * ka0 + ka1 * ka1;
#pragma unroll
  for (int m = 1; m < 64; m <<= 1) {
    sq += __shfl_xor(sq, m);
    sk += __shfl_xor(sk, m);
  }
  float qinv = 1.0f / fmaxf(sqrtf(sq), 1e-12f);
  float kinv = 1.0f / fmaxf(sqrtf(sk), 1e-12f);
  const int bh = b * kH + h;
  const size_t outb = ((size_t)bh * kT + t) * kK + c0;
  *(float2*)(qc + outb) = make_float2(qa0 * qinv, qa1 * qinv);
  *(float2*)(kc + outb) = make_float2(ka0 * kinv, ka1 * kinv);
  const size_t vtb = ((size_t)(bh * 8 + (c0 >> 4)) * kT + t) * 16 + (c0 & 15);
  *(float2*)(vt + vtb) = make_float2(va0, va1);
  u32 ug = *(const u32*)(graw + (size_t)bt * kHK + colofs);
  float Ae = expf(A_log[h]);
  float g0 = bflo(ug) + dt_bias[colofs];
  float g1 = bfhi(ug) + dt_bias[colofs + 1];
  float sp0 = (g0 > 15.f) ? g0 : log1pf(expf(g0));
  float sp1 = (g1 > 15.f) ? g1 : log1pf(expf(g1));
  *(float2*)(gdec + outb) = make_float2(-Ae * sp0, -Ae * sp1);
  if (lane == 0) {
    float bv = bflo((u32)fgb[(size_t)bt * 384 + 256 + h]);
    beta[(size_t)bh * kT + t] = sigmoidf(bv);
  }
}

// ---------------- KDA pass 1: per (bh,chunk) transforms --------------------
// Emits bf16 khat=k*e^G, qhat=q*e^G (layout [t][k]); kbar=k*e^{GC-G} now
// written TRANSPOSED per chunk ([k][16 t]) so p2 can stage it into LDS with
// aligned vector stores instead of a 16-way-bank-conflict scatter.
// f32 lam=e^{GC}, Winv=(I+B trilA)^{-1}B, M from the ROUNDED values.
__global__ __launch_bounds__(256) void kda_p1(
    const float* __restrict__ qc, const float* __restrict__ kc,
    const float* __restrict__ gk, const float* __restrict__ betap,
    u16* __restrict__ qhb, u16* __restrict__ khb, u16* __restrict__ kbt,
    float* __restrict__ lamC, float* __restrict__ winv,
    float* __restrict__ mmat) {
  __shared__ float kL[CC][132], qL[CC][132], gL[CC][132];
  __shared__ float As[CC][CC], Ms[CC][CC];
  __shared__ float bet[CC];
  const int tid = threadIdx.x;
  const int bh = blockIdx.x >> 7;
  const int ch = blockIdx.x & 127;
  const size_t base = ((size_t)bh * kT + ch * CC) * kK;
  const int e = tid * 8;
  const int t = e >> 7, k = e & 127;
  {
    *(float4*)&kL[t][k]     = *(const float4*)(kc + base + e);
    *(float4*)&kL[t][k + 4] = *(const float4*)(kc + base + e + 4);
    *(float4*)&qL[t][k]     = *(const float4*)(qc + base + e);
    *(float4*)&qL[t][k + 4] = *(const float4*)(qc + base + e + 4);
    *(float4*)&gL[t][k]     = *(const float4*)(gk + base + e);
    *(float4*)&gL[t][k + 4] = *(const float4*)(gk + base + e + 4);
    if (tid < CC) bet[tid] = betap[(size_t)bh * kT + ch * CC + tid];
  }
  __syncthreads();
  if (tid < kK) {        // inclusive cumsum of g over t -> G
    float a = gL[0][tid];
#pragma unroll
    for (int tt = 1; tt < CC; ++tt) { a += gL[tt][tid]; gL[tt][tid] = a; }
  }
  __syncthreads();
  float khr[8], qhr[8], kbw[8];
  u16 kbv[8];
  u32 pk[4] = {0,0,0,0}, pq[4] = {0,0,0,0};
#pragma unroll
  for (int j = 0; j < 8; ++j) {
    float G  = gL[t][k + j];
    float GC = gL[CC - 1][k + j];
    float eg = __expf(G);
    float kh = kL[t][k + j] * eg;
    float qh = qL[t][k + j] * eg;
    float kb = kL[t][k + j] * __expf(GC - G);
    u16 a = f2bf(kh), b_ = f2bf(qh), c = f2bf(kb);
    pk[j >> 1] |= ((u32)a)  << (16 * (j & 1));
    pq[j >> 1] |= ((u32)b_) << (16 * (j & 1));
    kbv[j] = c;
    khr[j] = bflo(a);
    qhr[j] = bflo(b_);
    kbw[j] = bflo((u32)c) * __expf(-GC);   // kbar * e^{-GC}
  }
  *(uint4*)(khb + base + e) = *(uint4*)pk;
  *(uint4*)(qhb + base + e) = *(uint4*)pq;
  {  // transposed kbar: [bh][ch][k][16 t]; L2 merges the u16 scatter lines
    const size_t kb2 = ((size_t)bh * NCH + ch) * (size_t)(kK * CC) +
                       (size_t)k * CC + t;
#pragma unroll
    for (int j = 0; j < 8; ++j) kbt[kb2 + (size_t)j * CC] = kbv[j];
  }
  if (tid < kK)
    lamC[((size_t)bh * NCH + ch) * kK + tid] = __expf(gL[CC - 1][tid]);
  __syncthreads();   // all GC reads done before overwrite
#pragma unroll
  for (int j = 0; j < 8; ++j) {
    kL[t][k + j] = khr[j];
    qL[t][k + j] = qhr[j];
    gL[t][k + j] = kbw[j];
  }
  __syncthreads();
  {  // A[t][s]=khat_t . (kbar_s e^{-GC}); M[t][s]=qhat_t . (kbar_s e^{-GC})
    const int t2 = tid >> 4, s = tid & 15;
    float av = 0.f, mv = 0.f;
    for (int kk = 0; kk < kK; ++kk) {
      float w = gL[s][kk];
      av = fmaf(kL[t2][kk], w, av);
      mv = fmaf(qL[t2][kk], w, mv);
    }
    As[t2][s] = (s < t2)  ? av : 0.f;
    Ms[t2][s] = (s <= t2) ? mv : 0.f;
  }
  __syncthreads();
  if (tid < CC) {  // X = (I + B trilA)^{-1} B, column s
    const int s = tid;
    float x[CC];
#pragma unroll
    for (int tt = 0; tt < CC; ++tt) {
      float sum = 0.f;
      for (int r = 0; r < tt; ++r) sum += As[tt][r] * x[r];
      x[tt] = ((tt == s) ? bet[tt] : 0.f) - bet[tt] * sum;
    }
    const size_t wb = ((size_t)bh * NCH + ch) * 256;
#pragma unroll
    for (int tt = 0; tt < CC; ++tt) winv[wb + tt * 16 + s] = x[tt];
  }
  mmat[((size_t)bh * NCH + ch) * 256 + tid] = Ms[tid >> 4][tid & 15];
}

// ---------------- KDA pass 2: MFMA chunk recurrence ------------------------
// 512 blocks = 32 bh x 16 v-splits(8 cols), 4 waves, ~64KB LDS -> 2 blocks/CU
// (2 waves/SIMD; independent blocks interleave across barriers). Wave w owns
// state rows k in [w*32,w*32+32). V-cols 8..15 of every B operand are zero,
// so state cols 8..15 stay exactly 0 and results are bit-identical to the
// 16-wide split. Per chunk:
//   T1 = V - Khat S0 ; U = Winv T1 ; O = Qhat S0 + M U ; S = lam*S0 + Kbar^T U
__global__ __launch_bounds__(256) void kda_p2(
    const u16* __restrict__ khb, const u16* __restrict__ qhb,
    const u16* __restrict__ kbt, const float* __restrict__ lamC,
    const float* __restrict__ winv, const float* __restrict__ mmat,
    const float* __restrict__ vt, float* __restrict__ yf) {
  __shared__ u16 khs[2][CC][136];
  __shared__ u16 qhs[2][CC][136];
  __shared__ u16 kbs[2][kK][40];   // [k][s], cols 16..39 stay zero
  __shared__ float vsx[2][CC][9];
  __shared__ float wsx[2][CC][17];
  __shared__ float msx[2][CC][17];
  __shared__ float lamx[2][kK];
  __shared__ u16 s0h[CC][136];     // S^T bf16-hi [v][k] (rows 8..15 zero)
  __shared__ u16 s0l[CC][136];     // S^T bf16-lo
  __shared__ float pd[4][CC][17];
  __shared__ float qd[4][CC][17];
  __shared__ float t1r[CC][9];
  __shared__ float ufx[CC][9];
  __shared__ u16 ush[CC][40];      // U^T bf16-hi [v][s], rows 8..15 & cols 16..39 zero
  __shared__ u16 usl[CC][40];
  const int tid = threadIdx.x;
  const int w = tid >> 6, lane = tid & 63;
  const int m15 = lane & 15, q = lane >> 4, q8 = q * 8;
  const int blk = blockIdx.x;
  const int bh = (blk & 7) + ((blk >> 7) << 3);  // same-bh blocks share XCD slot
  const int vs = (blk >> 3) & 15;
  const int cb = vs * 8;
  // zero init (state, zero-padded arrays)
  for (int i = tid; i < CC * 136 / 2; i += 256) { ((u32*)s0h)[i] = 0; ((u32*)s0l)[i] = 0; }
  for (int i = tid; i < 2 * kK * 40 / 2; i += 256) ((u32*)kbs)[i] = 0;
  for (int i = tid; i < CC * 40 / 2; i += 256) { ((u32*)ush)[i] = 0; ((u32*)usl)[i] = 0; }

  uint4 rkh, rqh, rkb; float rv, rw, rm, rl;
  auto loadCh = [&](int ch) {
    const size_t cbase = ((size_t)bh * kT + ch * CC) * kK;
    rkh = *(const uint4*)(khb + cbase + tid * 8);
    rqh = *(const uint4*)(qhb + cbase + tid * 8);
    rkb = *(const uint4*)(kbt + ((size_t)bh * NCH + ch) * (size_t)(kK * CC) + tid * 8);
    rv  = (tid < CC * 8)
            ? vt[((size_t)(bh * 8 + (vs >> 1)) * kT + ch * CC + (tid >> 3)) * 16 +
                 (vs & 1) * 8 + (tid & 7)]
            : 0.f;
    const size_t sm = (size_t)bh * NCH + ch;
    rw  = winv[sm * 256 + tid];
    rm  = mmat[sm * 256 + tid];
    rl  = (tid < kK) ? lamC[sm * kK + tid] : 0.f;
  };
  auto writeStage = [&](int b) {
    const int tr = tid >> 4, tc = (tid & 15) * 8;
    *(uint4*)&khs[b][tr][tc] = rkh;
    *(uint4*)&qhs[b][tr][tc] = rqh;
    *(uint4*)&kbs[b][tid >> 1][(tid & 1) * 8] = rkb;   // already [k][t] layout
    if (tid < CC * 8) vsx[b][tid >> 3][tid & 7] = rv;
    wsx[b][tr][tid & 15] = rw;
    msx[b][tr][tid & 15] = rm;
    if (tid < kK) lamx[b][tid] = rl;
  };

  f32x4 St[2] = {};
  loadCh(0);
  for (int ch = 0; ch < NCH; ++ch) {
    const int b = ch & 1;
    writeStage(b);
    if (ch + 1 < NCH) loadCh(ch + 1);
    __syncthreads();  // B1: stage + S0 hi/lo visible
    // phase A: wave-partial K-slice products
    short8 aK = *(const short8*)&khs[b][m15][w * 32 + q8];
    short8 aQ = *(const short8*)&qhs[b][m15][w * 32 + q8];
    short8 sH = *(const short8*)&s0h[m15][w * 32 + q8];
    short8 sL = *(const short8*)&s0l[m15][w * 32 + q8];
    f32x4 z = {0.f, 0.f, 0.f, 0.f};
    f32x4 P  = __builtin_amdgcn_mfma_f32_16x16x32_bf16(aK, sL, z, 0, 0, 0);
    P        = __builtin_amdgcn_mfma_f32_16x16x32_bf16(aK, sH, P, 0, 0, 0);
    f32x4 Qp = __builtin_amdgcn_mfma_f32_16x16x32_bf16(aQ, sL, z, 0, 0, 0);
    Qp       = __builtin_amdgcn_mfma_f32_16x16x32_bf16(aQ, sH, Qp, 0, 0, 0);
#pragma unroll
    for (int r = 0; r < 4; ++r) {
      pd[w][q * 4 + r][m15] = P[r];
      qd[w][q * 4 + r][m15] = Qp[r];
    }
    __syncthreads();  // B2
    const int tt = tid >> 3, vv = tid & 7;   // (t, v) for the 16x8 scalar phases
    float qs = 0.f;
    if (tid < 128) {
      float t1 = vsx[b][tt][vv] -
                 ((pd[0][tt][vv] + pd[1][tt][vv]) + (pd[2][tt][vv] + pd[3][tt][vv]));
      qs = (qd[0][tt][vv] + qd[1][tt][vv]) + (qd[2][tt][vv] + qd[3][tt][vv]);
      t1r[tt][vv] = t1;
    }
    __syncthreads();  // B3
    if (tid < 128) {
      float u = 0.f;
#pragma unroll
      for (int s = 0; s < CC; ++s) u = fmaf(wsx[b][tt][s], t1r[s][vv], u);
      ufx[tt][vv] = u;
      u16 uh = f2bf(u);
      ush[vv][tt] = uh;
      usl[vv][tt] = f2bf(u - bflo(uh));
    }
    __syncthreads();  // B4
    if (tid < 128) {
      float o = qs;
#pragma unroll
      for (int s = 0; s < CC; ++s) o = fmaf(msx[b][tt][s], ufx[s][vv], o);
      yf[((size_t)bh * kT + ch * CC + tt) * kV + cb + vv] = o;
    }
    // state update: S = lam*S + Kbar^T U  (hi/lo mfma pair per tile)
    short8 bH = *(const short8*)&ush[m15][q8];
    short8 bL = *(const short8*)&usl[m15][q8];
#pragma unroll
    for (int j = 0; j < 2; ++j) {
      const int kt = w * 32 + j * 16;
      f32x4 S = St[j];
#pragma unroll
      for (int r = 0; r < 4; ++r) S[r] *= lamx[b][kt + q * 4 + r];
      short8 aB = *(const short8*)&kbs[b][kt + m15][q8];
      S = __builtin_amdgcn_mfma_f32_16x16x32_bf16(aB, bL, S, 0, 0, 0);
      S = __builtin_amdgcn_mfma_f32_16x16x32_bf16(aB, bH, S, 0, 0, 0);
      St[j] = S;
      u16 h0 = f2bf(S[0]), h1 = f2bf(S[1]), h2 = f2bf(S[2]), h3 = f2bf(S[3]);
      uint2 hw; hw.x = (u32)h0 | ((u32)h1 << 16); hw.y = (u32)h2 | ((u32)h3 << 16);
      *(uint2*)&s0h[m15][kt + q * 4] = hw;
      uint2 lw;
      lw.x = (u32)f2bf(S[0] - bflo(h0)) | ((u32)f2bf(S[1] - bflo(h1)) << 16);
      lw.y = (u32)f2bf(S[2] - bflo(h2)) | ((u32)f2bf(S[3] - bflo(h3)) << 16);
      *(uint2*)&s0l[m15][kt + q * 4] = lw;
    }
  }
}

// ---------------- rmsnorm * o_norm_w * sigmoid(gate+bg) -> bf16 -----------
__global__ __launch_bounds__(256) void postk(
    const float* __restrict__ yf, const u16* __restrict__ gateb,
    const float* __restrict__ bg, const float* __restrict__ onw,
    u16* __restrict__ ygb) {
  const int wid  = blockIdx.x * 4 + (threadIdx.x >> 6);
  const int lane = threadIdx.x & 63;
  const int h  = wid & 15;
  const int bt = wid >> 4;
  const int t  = bt & (kT - 1);
  const int b  = bt >> 11;
  const int v0 = lane * 2;
  const size_t yi = ((size_t)(b * kH + h) * kT + t) * kV + v0;
  float2 yv = *(const float2*)(yf + yi);
  float s = yv.x * yv.x + yv.y * yv.y;
#pragma unroll
  for (int m = 1; m < 64; m <<= 1) s += __shfl_xor(s, m);
  float scale = rsqrtf(s * (1.0f / 128.0f) + 1.1920929e-07f);
  const size_t gi = (size_t)bt * kHV + (size_t)h * kV + v0;
  u32 ug = *(const u32*)(gateb + gi);
  float g0 = bflo(ug) + bg[h * kV + v0];
  float g1 = bfhi(ug) + bg[h * kV + v0 + 1];
  float r0 = yv.x * scale * onw[v0] * sigmoidf(g0);
  float r1 = yv.y * scale * onw[v0 + 1] * sigmoidf(g1);
  *(u32*)(ygb + gi) = (u32)f2bf(r0) | ((u32)f2bf(r1) << 16);
}

// ---------------- host launcher ----------------
extern "C" void kernel_launch(void* const* d_in, const int* in_sizes, int n_in,
                              void* d_out, int out_size, void* d_ws, size_t ws_size,
                              hipStream_t stream) {
  (void)in_sizes; (void)n_in; (void)out_size; (void)ws_size;
  const float* x    = (const float*)d_in[0];
  const float* Wq   = (const float*)d_in[1];
  const float* Wk   = (const float*)d_in[2];
  const float* Wv   = (const float*)d_in[3];
  const float* Wf1  = (const float*)d_in[4];
  const float* Wf2  = (const float*)d_in[5];
  const float* Wb   = (const float*)d_in[6];
  const float* Wg1  = (const float*)d_in[7];
  const float* Wg2  = (const float*)d_in[8];
  const float* bg   = (const float*)d_in[9];
  const float* onw  = (const float*)d_in[10];
  const float* Wout = (const float*)d_in[11];
  const float* A_log   = (const float*)d_in[12];
  const float* dt_bias = (const float*)d_in[13];
  const float* qcw  = (const float*)d_in[14];
  const float* kcw  = (const float*)d_in[15];
  const float* vcw  = (const float*)d_in[16];

  char* ws = (char*)d_ws;
  u16* xb     = (u16*)(ws + OFF_XB);
  u16* wqkv   = (u16*)(ws + OFF_WQKV);
  u16* wf1b   = (u16*)(ws + OFF_WF1B);
  u16* wg1b   = (u16*)(ws + OFF_WG1B);
  u16* wbp    = (u16*)(ws + OFF_WBP);
  u16* wf2b   = (u16*)(ws + OFF_WF2B);
  u16* wg2b   = (u16*)(ws + OFF_WG2B);
  u16* woutb  = (u16*)(ws + OFF_WOUTB);
  u16* fgb    = (u16*)(ws + OFF_FGB);
  u16* qkvraw = (u16*)(ws + OFF_QKVR);
  u16* graw   = (u16*)(ws + OFF_GRAW);
  u16* gateb  = (u16*)(ws + OFF_GATEB);
  u16* qhb    = (u16*)(ws + OFF_QHB);
  u16* khb    = (u16*)(ws + OFF_KHB);
  u16* kbb    = (u16*)(ws + OFF_KBB);
  u16* ygb    = (u16*)(ws + OFF_YGB);
  float* qcf   = (float*)(ws + OFF_QC);
  float* kcf   = (float*)(ws + OFF_KC);
  float* vtf   = (float*)(ws + OFF_VT);
  float* gkf   = (float*)(ws + OFF_GK);
  float* betaf = (float*)(ws + OFF_BETA);
  float* yff   = (float*)(ws + OFF_YF);
  float* lamf  = (float*)(ws + OFF_LAM);
  float* winvf = (float*)(ws + OFF_WINV);
  float* mmf   = (float*)(ws + OFF_MM);

  cast_all<<<25600, 256, 0, stream>>>(x, Wq, Wk, Wv, Wout, Wf1, Wg1, Wf2, Wg2,
                                      xb, wqkv, woutb, wf1b, wg1b, wf2b, wg2b);
  pad_wb<<<(128 * 2048 / 4 + 255) / 256, 256, 0, stream>>>(Wb, wbp);

  dim3 blk(256);
  // qkv: [4096,6144] = x @ [Wq;Wk;Wv]^T
  gemm_bt<true><<<dim3(kM / 128, 6144 / 128), blk, 0, stream>>>(
      xb, wqkv, qkvraw, kD, kD, 6144, kD);
  // fgb: [4096,384] = x @ [Wf1;Wg1;Wbp]^T
  gemm_bt<true><<<dim3(kM / 128, 384 / 128), blk, 0, stream>>>(
      xb, wf1b, fgb, kD, kD, 384, kD);
  // graw: [4096,2048] = f1 @ Wf2^T   (A = fgb cols 0..127, lda 384)
  gemm_bt<true><<<dim3(kM / 128, kHK / 128), blk, 0, stream>>>(
      fgb, wf2b, graw, 384, kV, kHK, kV);
  // gateb: [4096,2048] = g1 @ Wg2^T  (A = fgb cols 128..255)
  gemm_bt<true><<<dim3(kM / 128, kHV / 128), blk, 0, stream>>>(
      fgb + 128, wg2b, gateb, 384, kV, kHV, kV);

  convprep<<<kB * kT * kH / 4, 256, 0, stream>>>(qkvraw, graw, fgb,
                                                 qcw, kcw, vcw, A_log, dt_bias,
                                                 qcf, kcf, vtf, gkf, betaf);

  kda_p1<<<32 * NCH, 256, 0, stream>>>(qcf, kcf, gkf, betaf,
                                       qhb, khb, kbb, lamf, winvf, mmf);
  kda_p2<<<512, 256, 0, stream>>>(khb, qhb, kbb, lamf, winvf, mmf, vtf, yff);

  postk<<<kB * kT * kH / 4, 256, 0, stream>>>(yff, gateb, bg, onw, ygb);

  // out: [4096,2048] = yg @ Wout^T
  gemm_bt<false><<<dim3(kM / 128, kD / 128), blk, 0, stream>>>(
      ygb, woutb, (float*)d_out, kHV, kHV, kD, kHV);
}

// Round 2
// 717.604 us; speedup vs baseline: 1.1720x; 1.1259x over previous
//
#include <hip/hip_runtime.h>

typedef unsigned short u16;
typedef unsigned int u32;

using short8 = __attribute__((ext_vector_type(8))) short;
using f32x4  = __attribute__((ext_vector_type(4))) float;

constexpr int kB = 2, kT = 2048, kD = 2048, kH = 16, kK = 128, kV = 128;
constexpr int kM  = kB * kT;   // 4096 tokens
constexpr int kHK = kH * kK;   // 2048
constexpr int kHV = kH * kV;   // 2048
constexpr int CC  = 16;        // scan chunk length
constexpr int NCH = kT / CC;   // 128 chunks

// ---------------- workspace layout (bytes). Overlays are deliberate. -------
// timeline: casts -> gemms(qkv,fgb,graw,gateb) -> convprep -> p1 -> p2 -> postk -> out-gemm
constexpr size_t OFF_XB    = 0;          // bf16 x [4096][2048] (dead after gemms)
constexpr size_t OFF_WQKV  = 16777216;   // bf16 [6144][2048] = Wq|Wk|Wv stacked (dead after qkv gemm)
constexpr size_t OFF_QC    = 0;          // f32 qc [32][2048][128] 33.5MB (convprep out; over XB+Wq+Wk)
constexpr size_t OFF_YF    = 0;          // f32 y [32][2048][128] (p2 out; qc dead after p1)
constexpr size_t OFF_WF1B  = 41943040;   // bf16 Wf1 [128][2048]
constexpr size_t OFF_WG1B  = 42467328;   // bf16 Wg1
constexpr size_t OFF_WBP   = 42991616;   // bf16 Wb padded [128][2048]  (F1|G1|BP contiguous = N=384)
constexpr size_t OFF_WF2B  = 43515904;   // bf16 Wf2
constexpr size_t OFF_WG2B  = 44040192;   // bf16 Wg2
constexpr size_t OFF_FGB   = 44564480;   // bf16 fgb [4096][384] (f1|g1|braw)
constexpr size_t OFF_QKVR  = 48758784;   // bf16 qkvraw [4096][6144] 50.3MB (dead after convprep)
constexpr size_t OFF_QHB   = 48758784;   // bf16 qhat [32][2048][128] (p1 out, over qkvraw)
constexpr size_t OFF_KBB   = 65536000;   // bf16 kbar TRANSPOSED [32][128ch][128k][16t]
constexpr size_t OFF_KHB   = 82313216;   // bf16 khat
constexpr size_t OFF_YGB   = 82313216;   // bf16 y-gated (postk out, khb dead by then)
constexpr size_t OFF_GRAW  = 99090432;   // bf16 g_raw [4096][2048] (dead after convprep)
constexpr size_t OFF_LAM   = 99090432;   // f32 lam  [32][128][128] (p1 out, over graw)
constexpr size_t OFF_WINV  = 101187584;  // f32 winv [32][128][256]
constexpr size_t OFF_MM    = 105381888;  // f32 M    [32][128][256]
constexpr size_t OFF_GATEB = 115867648;  // bf16 gate [4096][2048]
constexpr size_t OFF_WOUTB = 132644864;  // bf16 Wout
constexpr size_t OFF_KC    = 141033472;  // f32 kc
constexpr size_t OFF_VT    = 174587904;  // f32 v transposed [bh*8+vs][t][16]
constexpr size_t OFF_GK    = 208142336;  // f32 log-decay g
constexpr size_t OFF_BETA  = 241696768;  // f32 beta [32][2048]
// total 241958912 bytes (~231 MB), unchanged

// ---------------- small helpers ----------------
__device__ __forceinline__ u16 f2bf(float f) {
  union { float f; u32 u; } a; a.f = f;
  u32 u = a.u;
  u += 0x7fffu + ((u >> 16) & 1u);   // round-to-nearest-even
  return (u16)(u >> 16);
}
__device__ __forceinline__ float bflo(u32 u) {
  union { u32 u; float f; } a; a.u = u << 16; return a.f;
}
__device__ __forceinline__ float bfhi(u32 u) {
  union { u32 u; float f; } a; a.u = u & 0xffff0000u; return a.f;
}
// fast sigmoid: v_exp + v_rcp (~1 ulp each; all consumers round to bf16)
__device__ __forceinline__ float sigmoidf(float x) {
  return __builtin_amdgcn_rcpf(1.0f + __expf(-x));
}

#define GL_AS1 __attribute__((address_space(1)))
#define GL_AS3 __attribute__((address_space(3)))
__device__ __forceinline__ void async_lds16(const void* g, void* l) {
  __builtin_amdgcn_global_load_lds((GL_AS1 u32*)(size_t)g,
                                   (GL_AS3 u32*)(u32)(size_t)l, 16, 0, 0);
}

// ---------------- fused cast of all f32->bf16 weights/x --------------------
__global__ __launch_bounds__(256) void cast_all(
    const float* __restrict__ x, const float* __restrict__ Wq,
    const float* __restrict__ Wk, const float* __restrict__ Wv,
    const float* __restrict__ Wout, const float* __restrict__ Wf1,
    const float* __restrict__ Wg1, const float* __restrict__ Wf2,
    const float* __restrict__ Wg2,
    u16* __restrict__ xb, u16* __restrict__ wqkv, u16* __restrict__ woutb,
    u16* __restrict__ wf1b, u16* __restrict__ wg1b, u16* __restrict__ wf2b,
    u16* __restrict__ wg2b) {
  long qi = (long)blockIdx.x * 256 + threadIdx.x;   // float4 index
  const float* src; u16* dst; long off;
  if (qi < 2097152)      { src = x;    dst = xb;             off = qi; }
  else if (qi < 3145728) { src = Wq;   dst = wqkv;           off = qi - 2097152; }
  else if (qi < 4194304) { src = Wk;   dst = wqkv + 4194304; off = qi - 3145728; }
  else if (qi < 5242880) { src = Wv;   dst = wqkv + 8388608; off = qi - 4194304; }
  else if (qi < 6291456) { src = Wout; dst = woutb;          off = qi - 5242880; }
  else if (qi < 6356992) { src = Wf1;  dst = wf1b;           off = qi - 6291456; }
  else if (qi < 6422528) { src = Wg1;  dst = wg1b;           off = qi - 6356992; }
  else if (qi < 6488064) { src = Wf2;  dst = wf2b;           off = qi - 6422528; }
  else                   { src = Wg2;  dst = wg2b;           off = qi - 6488064; }
  long i = off * 4;
  float4 v = *(const float4*)(src + i);
  uint2 st;
  st.x = (u32)f2bf(v.x) | ((u32)f2bf(v.y) << 16);
  st.y = (u32)f2bf(v.z) | ((u32)f2bf(v.w) << 16);
  *(uint2*)(dst + i) = st;
}

// Wb [16,2048] f32 -> [128,2048] bf16 zero-padded
__global__ __launch_bounds__(256) void pad_wb(const float* __restrict__ Wb,
                                              u16* __restrict__ out) {
  int i = (blockIdx.x * 256 + threadIdx.x) * 4;  // < 262144
  int row = i >> 11;
  uint2 st; st.x = 0; st.y = 0;
  if (row < 16) {
    float4 v = *(const float4*)(Wb + i);
    st.x = (u32)f2bf(v.x) | ((u32)f2bf(v.y) << 16);
    st.y = (u32)f2bf(v.z) | ((u32)f2bf(v.w) << 16);
  }
  *(uint2*)(out + i) = st;
}

// ---------------- bf16 MFMA GEMM:  C[m,n] = sum_k A[m,k] * B[n,k] ----------
template <bool BF16OUT>
__global__ __launch_bounds__(256) void gemm_bt(const u16* __restrict__ A,
                                               const u16* __restrict__ B,
                                               void* __restrict__ Cout,
                                               int lda, int ldb, int ldc, int K) {
  __shared__ u16 As[128 * 32];
  __shared__ u16 Bs[128 * 32];
  const int tid  = threadIdx.x;
  const int lane = tid & 63;
  const int wave = tid >> 6;
  const int wm = (wave >> 1) * 64;
  const int wn = (wave & 1) * 64;
  const long row0 = (long)blockIdx.x * 128;
  const long col0 = (long)blockIdx.y * 128;
  const int srow = tid >> 2;
  const int scol = (tid & 3) * 8;
  const u16* aptr = A + (row0 + srow) * (size_t)lda + scol;
  const u16* bptr = B + (col0 + srow) * (size_t)ldb + scol;
  u16* asd  = &As[tid * 8];
  u16* asd2 = &As[2048 + tid * 8];
  u16* bsd  = &Bs[tid * 8];
  u16* bsd2 = &Bs[2048 + tid * 8];
  const int mrow = lane & 15;
  const int kq = (lane >> 4) * 8;
  f32x4 acc[4][4] = {};
  for (int k0 = 0; k0 < K; k0 += 32) {
    async_lds16(aptr, asd);
    async_lds16(aptr + (size_t)64 * lda, asd2);
    async_lds16(bptr, bsd);
    async_lds16(bptr + (size_t)64 * ldb, bsd2);
    aptr += 32; bptr += 32;
    __syncthreads();
    short8 af[4], bfr[4];
#pragma unroll
    for (int i = 0; i < 4; ++i)
      af[i] = *(const short8*)(&As[(wm + i * 16 + mrow) * 32 + kq]);
#pragma unroll
    for (int j = 0; j < 4; ++j)
      bfr[j] = *(const short8*)(&Bs[(wn + j * 16 + mrow) * 32 + kq]);
#pragma unroll
    for (int i = 0; i < 4; ++i)
#pragma unroll
      for (int j = 0; j < 4; ++j)
        acc[i][j] = __builtin_amdgcn_mfma_f32_16x16x32_bf16(af[i], bfr[j], acc[i][j], 0, 0, 0);
    __syncthreads();
  }
  const int cn = lane & 15;
  const int rq = (lane >> 4) * 4;
#pragma unroll
  for (int i = 0; i < 4; ++i)
#pragma unroll
    for (int j = 0; j < 4; ++j) {
      size_t r = (size_t)(row0 + wm + i * 16 + rq);
      size_t c = (size_t)(col0 + wn + j * 16 + cn);
#pragma unroll
      for (int rr = 0; rr < 4; ++rr) {
        if constexpr (BF16OUT)
          ((u16*)Cout)[(r + rr) * ldc + c] = f2bf(acc[i][j][rr]);
        else
          ((float*)Cout)[(r + rr) * ldc + c] = acc[i][j][rr];
      }
    }
}

// ---------------- conv(4-tap causal) + silu + l2norm + g + beta ------------
// One 32-lane half-wave per (bt,h) row; 4 channels/lane. All transcendentals
// via fast HW ops (v_exp/v_log/v_rcp/v_sqrt) — consumers round to bf16 anyway.
__global__ __launch_bounds__(256) void convprep(
    const u16* __restrict__ qkv, const u16* __restrict__ graw,
    const u16* __restrict__ fgb,
    const float* __restrict__ qcw, const float* __restrict__ kcw,
    const float* __restrict__ vcw, const float* __restrict__ A_log,
    const float* __restrict__ dt_bias,
    float* __restrict__ qc, float* __restrict__ kc, float* __restrict__ vt,
    float* __restrict__ gdec, float* __restrict__ beta) {
  const int wid = blockIdx.x * 8 + (threadIdx.x >> 5);  // (b*T+t)*H + h
  const int l32 = threadIdx.x & 31;
  const int h  = wid & 15;
  const int bt = wid >> 4;        // b*T + t
  const int t  = bt & (kT - 1);
  const int b  = bt >> 11;
  const int c0 = l32 * 4;
  const size_t colofs = (size_t)h * kK + c0;
  const size_t rowb = (size_t)bt * 6144 + colofs;
  // conv weights: [ch][tap], 4 channels = 16 contiguous floats per matrix
  float wqt[4][4], wkt[4][4], wvt[4][4];
#pragma unroll
  for (int j = 0; j < 4; ++j) {
    *(float4*)wqt[j] = *(const float4*)(qcw + (colofs + j) * 4);
    *(float4*)wkt[j] = *(const float4*)(kcw + (colofs + j) * 4);
    *(float4*)wvt[j] = *(const float4*)(vcw + (colofs + j) * 4);
  }
  float qa[4] = {0.f, 0.f, 0.f, 0.f};
  float ka[4] = {0.f, 0.f, 0.f, 0.f};
  float va[4] = {0.f, 0.f, 0.f, 0.f};
#pragma unroll
  for (int i = 0; i < 4; ++i) {
    int tt = t - 3 + i;
    if (tt >= 0) {   // wave-uniform branch
      size_t ro = rowb - (size_t)(3 - i) * 6144;
      uint2 uq = *(const uint2*)(qkv + ro);
      uint2 uk = *(const uint2*)(qkv + ro + 2048);
      uint2 uv = *(const uint2*)(qkv + ro + 4096);
      float q0 = bflo(uq.x), q1 = bfhi(uq.x), q2 = bflo(uq.y), q3 = bfhi(uq.y);
      float k0 = bflo(uk.x), k1 = bfhi(uk.x), k2 = bflo(uk.y), k3 = bfhi(uk.y);
      float v0 = bflo(uv.x), v1 = bfhi(uv.x), v2 = bflo(uv.y), v3 = bfhi(uv.y);
      qa[0] = fmaf(q0, wqt[0][i], qa[0]); qa[1] = fmaf(q1, wqt[1][i], qa[1]);
      qa[2] = fmaf(q2, wqt[2][i], qa[2]); qa[3] = fmaf(q3, wqt[3][i], qa[3]);
      ka[0] = fmaf(k0, wkt[0][i], ka[0]); ka[1] = fmaf(k1, wkt[1][i], ka[1]);
      ka[2] = fmaf(k2, wkt[2][i], ka[2]); ka[3] = fmaf(k3, wkt[3][i], ka[3]);
      va[0] = fmaf(v0, wvt[0][i], va[0]); va[1] = fmaf(v1, wvt[1][i], va[1]);
      va[2] = fmaf(v2, wvt[2][i], va[2]); va[3] = fmaf(v3, wvt[3][i], va[3]);
    }
  }
  float sq = 0.f, sk = 0.f;
#pragma unroll
  for (int j = 0; j < 4; ++j) {
    qa[j] *= sigmoidf(qa[j]);            // silu
    ka[j] *= sigmoidf(ka[j]);
    va[j] *= sigmoidf(va[j]);
    sq = fmaf(qa[j], qa[j], sq);
    sk = fmaf(ka[j], ka[j], sk);
  }
#pragma unroll
  for (int m = 1; m < 32; m <<= 1) {     // reduce within the 32-lane row
    sq += __shfl_xor(sq, m);
    sk += __shfl_xor(sk, m);
  }
  float qinv = __builtin_amdgcn_rcpf(fmaxf(__builtin_amdgcn_sqrtf(sq), 1e-12f));
  float kinv = __builtin_amdgcn_rcpf(fmaxf(__builtin_amdgcn_sqrtf(sk), 1e-12f));
  const int bh = b * kH + h;
  const size_t outb = ((size_t)bh * kT + t) * kK + c0;
  *(float4*)(qc + outb) =
      make_float4(qa[0] * qinv, qa[1] * qinv, qa[2] * qinv, qa[3] * qinv);
  *(float4*)(kc + outb) =
      make_float4(ka[0] * kinv, ka[1] * kinv, ka[2] * kinv, ka[3] * kinv);
  const size_t vtb = ((size_t)(bh * 8 + (c0 >> 4)) * kT + t) * 16 + (c0 & 15);
  *(float4*)(vt + vtb) = make_float4(va[0], va[1], va[2], va[3]);
  // decay g = -exp(A_log) * softplus(graw + dt_bias)
  uint2 ug = *(const uint2*)(graw + (size_t)bt * kHK + colofs);
  float Ae = __expf(A_log[h]);
  float4 db = *(const float4*)(dt_bias + colofs);
  float g0 = bflo(ug.x) + db.x;
  float g1 = bfhi(ug.x) + db.y;
  float g2 = bflo(ug.y) + db.z;
  float g3 = bfhi(ug.y) + db.w;
  float sp0 = (g0 > 15.f) ? g0 : __logf(1.f + __expf(g0));
  float sp1 = (g1 > 15.f) ? g1 : __logf(1.f + __expf(g1));
  float sp2 = (g2 > 15.f) ? g2 : __logf(1.f + __expf(g2));
  float sp3 = (g3 > 15.f) ? g3 : __logf(1.f + __expf(g3));
  *(float4*)(gdec + outb) = make_float4(-Ae * sp0, -Ae * sp1, -Ae * sp2, -Ae * sp3);
  if (l32 == 0) {
    float bv = bflo((u32)fgb[(size_t)bt * 384 + 256 + h]);
    beta[(size_t)bh * kT + t] = sigmoidf(bv);
  }
}

// ---------------- KDA pass 1: per (bh,chunk) transforms --------------------
// Emits bf16 khat=k*e^G, qhat=q*e^G (layout [t][k]); kbar=k*e^{GC-G} written
// TRANSPOSED per chunk ([k][16 t]) so p2 can stage it with aligned vector
// stores. f32 lam=e^{GC}, Winv=(I+B trilA)^{-1}B, M from the ROUNDED values.
__global__ __launch_bounds__(256) void kda_p1(
    const float* __restrict__ qc, const float* __restrict__ kc,
    const float* __restrict__ gk, const float* __restrict__ betap,
    u16* __restrict__ qhb, u16* __restrict__ khb, u16* __restrict__ kbt,
    float* __restrict__ lamC, float* __restrict__ winv,
    float* __restrict__ mmat) {
  __shared__ float kL[CC][132], qL[CC][132], gL[CC][132];
  __shared__ float As[CC][CC], Ms[CC][CC];
  __shared__ float bet[CC];
  const int tid = threadIdx.x;
  const int bh = blockIdx.x >> 7;
  const int ch = blockIdx.x & 127;
  const size_t base = ((size_t)bh * kT + ch * CC) * kK;
  const int e = tid * 8;
  const int t = e >> 7, k = e & 127;
  {
    *(float4*)&kL[t][k]     = *(const float4*)(kc + base + e);
    *(float4*)&kL[t][k + 4] = *(const float4*)(kc + base + e + 4);
    *(float4*)&qL[t][k]     = *(const float4*)(qc + base + e);
    *(float4*)&qL[t][k + 4] = *(const float4*)(qc + base + e + 4);
    *(float4*)&gL[t][k]     = *(const float4*)(gk + base + e);
    *(float4*)&gL[t][k + 4] = *(const float4*)(gk + base + e + 4);
    if (tid < CC) bet[tid] = betap[(size_t)bh * kT + ch * CC + tid];
  }
  __syncthreads();
  if (tid < kK) {        // inclusive cumsum of g over t -> G
    float a = gL[0][tid];
#pragma unroll
    for (int tt = 1; tt < CC; ++tt) { a += gL[tt][tid]; gL[tt][tid] = a; }
  }
  __syncthreads();
  float khr[8], qhr[8], kbw[8];
  u16 kbv[8];
  u32 pk[4] = {0,0,0,0}, pq[4] = {0,0,0,0};
#pragma unroll
  for (int j = 0; j < 8; ++j) {
    float G  = gL[t][k + j];
    float GC = gL[CC - 1][k + j];
    float eg = __expf(G);
    float kh = kL[t][k + j] * eg;
    float qh = qL[t][k + j] * eg;
    float kb = kL[t][k + j] * __expf(GC - G);
    u16 a = f2bf(kh), b_ = f2bf(qh), c = f2bf(kb);
    pk[j >> 1] |= ((u32)a)  << (16 * (j & 1));
    pq[j >> 1] |= ((u32)b_) << (16 * (j & 1));
    kbv[j] = c;
    khr[j] = bflo(a);
    qhr[j] = bflo(b_);
    kbw[j] = bflo((u32)c) * __expf(-GC);   // kbar * e^{-GC}
  }
  *(uint4*)(khb + base + e) = *(uint4*)pk;
  *(uint4*)(qhb + base + e) = *(uint4*)pq;
  {  // transposed kbar: [bh][ch][k][16 t]; L2 merges the u16 scatter lines
    const size_t kb2 = ((size_t)bh * NCH + ch) * (size_t)(kK * CC) +
                       (size_t)k * CC + t;
#pragma unroll
    for (int j = 0; j < 8; ++j) kbt[kb2 + (size_t)j * CC] = kbv[j];
  }
  if (tid < kK)
    lamC[((size_t)bh * NCH + ch) * kK + tid] = __expf(gL[CC - 1][tid]);
  __syncthreads();   // all GC reads done before overwrite
#pragma unroll
  for (int j = 0; j < 8; ++j) {
    kL[t][k + j] = khr[j];
    qL[t][k + j] = qhr[j];
    gL[t][k + j] = kbw[j];
  }
  __syncthreads();
  {  // A[t][s]=khat_t . (kbar_s e^{-GC}); M[t][s]=qhat_t . (kbar_s e^{-GC})
    const int t2 = tid >> 4, s = tid & 15;
    float av = 0.f, mv = 0.f;
    for (int kk = 0; kk < kK; ++kk) {
      float w = gL[s][kk];
      av = fmaf(kL[t2][kk], w, av);
      mv = fmaf(qL[t2][kk], w, mv);
    }
    As[t2][s] = (s < t2)  ? av : 0.f;
    Ms[t2][s] = (s <= t2) ? mv : 0.f;
  }
  __syncthreads();
  if (tid < CC) {  // X = (I + B trilA)^{-1} B, column s
    const int s = tid;
    float x[CC];
#pragma unroll
    for (int tt = 0; tt < CC; ++tt) {
      float sum = 0.f;
      for (int r = 0; r < tt; ++r) sum += As[tt][r] * x[r];
      x[tt] = ((tt == s) ? bet[tt] : 0.f) - bet[tt] * sum;
    }
    const size_t wb = ((size_t)bh * NCH + ch) * 256;
#pragma unroll
    for (int tt = 0; tt < CC; ++tt) winv[wb + tt * 16 + s] = x[tt];
  }
  mmat[((size_t)bh * NCH + ch) * 256 + tid] = Ms[tid >> 4][tid & 15];
}

// ---------------- KDA pass 2: MFMA chunk recurrence ------------------------
// 512 blocks = 32 bh x 16 v-splits(8 cols), 4 waves, ~64KB LDS -> 2 blocks/CU
// (2 waves/SIMD; independent blocks interleave across barriers). Wave w owns
// state rows k in [w*32,w*32+32). V-cols 8..15 of every B operand are zero,
// so state cols 8..15 stay exactly 0 and results are bit-identical to the
// 16-wide split. Per chunk:
//   T1 = V - Khat S0 ; U = Winv T1 ; O = Qhat S0 + M U ; S = lam*S0 + Kbar^T U
__global__ __launch_bounds__(256) void kda_p2(
    const u16* __restrict__ khb, const u16* __restrict__ qhb,
    const u16* __restrict__ kbt, const float* __restrict__ lamC,
    const float* __restrict__ winv, const float* __restrict__ mmat,
    const float* __restrict__ vt, float* __restrict__ yf) {
  __shared__ u16 khs[2][CC][136];
  __shared__ u16 qhs[2][CC][136];
  __shared__ u16 kbs[2][kK][40];   // [k][s], cols 16..39 stay zero
  __shared__ float vsx[2][CC][9];
  __shared__ float wsx[2][CC][17];
  __shared__ float msx[2][CC][17];
  __shared__ float lamx[2][kK];
  __shared__ u16 s0h[CC][136];     // S^T bf16-hi [v][k] (rows 8..15 zero)
  __shared__ u16 s0l[CC][136];     // S^T bf16-lo
  __shared__ float pd[4][CC][17];
  __shared__ float qd[4][CC][17];
  __shared__ float t1r[CC][9];
  __shared__ float ufx[CC][9];
  __shared__ u16 ush[CC][40];      // U^T bf16-hi [v][s], rows 8..15 & cols 16..39 zero
  __shared__ u16 usl[CC][40];
  const int tid = threadIdx.x;
  const int w = tid >> 6, lane = tid & 63;
  const int m15 = lane & 15, q = lane >> 4, q8 = q * 8;
  const int blk = blockIdx.x;
  const int bh = (blk & 7) + ((blk >> 7) << 3);  // same-bh blocks share XCD slot
  const int vs = (blk >> 3) & 15;
  const int cb = vs * 8;
  // zero init (state, zero-padded arrays)
  for (int i = tid; i < CC * 136 / 2; i += 256) { ((u32*)s0h)[i] = 0; ((u32*)s0l)[i] = 0; }
  for (int i = tid; i < 2 * kK * 40 / 2; i += 256) ((u32*)kbs)[i] = 0;
  for (int i = tid; i < CC * 40 / 2; i += 256) { ((u32*)ush)[i] = 0; ((u32*)usl)[i] = 0; }

  uint4 rkh, rqh, rkb; float rv, rw, rm, rl;
  auto loadCh = [&](int ch) {
    const size_t cbase = ((size_t)bh * kT + ch * CC) * kK;
    rkh = *(const uint4*)(khb + cbase + tid * 8);
    rqh = *(const uint4*)(qhb + cbase + tid * 8);
    rkb = *(const uint4*)(kbt + ((size_t)bh * NCH + ch) * (size_t)(kK * CC) + tid * 8);
    rv  = (tid < CC * 8)
            ? vt[((size_t)(bh * 8 + (vs >> 1)) * kT + ch * CC + (tid >> 3)) * 16 +
                 (vs & 1) * 8 + (tid & 7)]
            : 0.f;
    const size_t sm = (size_t)bh * NCH + ch;
    rw  = winv[sm * 256 + tid];
    rm  = mmat[sm * 256 + tid];
    rl  = (tid < kK) ? lamC[sm * kK + tid] : 0.f;
  };
  auto writeStage = [&](int b) {
    const int tr = tid >> 4, tc = (tid & 15) * 8;
    *(uint4*)&khs[b][tr][tc] = rkh;
    *(uint4*)&qhs[b][tr][tc] = rqh;
    *(uint4*)&kbs[b][tid >> 1][(tid & 1) * 8] = rkb;   // already [k][t] layout
    if (tid < CC * 8) vsx[b][tid >> 3][tid & 7] = rv;
    wsx[b][tr][tid & 15] = rw;
    msx[b][tr][tid & 15] = rm;
    if (tid < kK) lamx[b][tid] = rl;
  };

  f32x4 St[2] = {};
  loadCh(0);
  for (int ch = 0; ch < NCH; ++ch) {
    const int b = ch & 1;
    writeStage(b);
    if (ch + 1 < NCH) loadCh(ch + 1);
    __syncthreads();  // B1: stage + S0 hi/lo visible
    // phase A: wave-partial K-slice products
    short8 aK = *(const short8*)&khs[b][m15][w * 32 + q8];
    short8 aQ = *(const short8*)&qhs[b][m15][w * 32 + q8];
    short8 sH = *(const short8*)&s0h[m15][w * 32 + q8];
    short8 sL = *(const short8*)&s0l[m15][w * 32 + q8];
    f32x4 z = {0.f, 0.f, 0.f, 0.f};
    f32x4 P  = __builtin_amdgcn_mfma_f32_16x16x32_bf16(aK, sL, z, 0, 0, 0);
    P        = __builtin_amdgcn_mfma_f32_16x16x32_bf16(aK, sH, P, 0, 0, 0);
    f32x4 Qp = __builtin_amdgcn_mfma_f32_16x16x32_bf16(aQ, sL, z, 0, 0, 0);
    Qp       = __builtin_amdgcn_mfma_f32_16x16x32_bf16(aQ, sH, Qp, 0, 0, 0);
#pragma unroll
    for (int r = 0; r < 4; ++r) {
      pd[w][q * 4 + r][m15] = P[r];
      qd[w][q * 4 + r][m15] = Qp[r];
    }
    __syncthreads();  // B2
    const int tt = tid >> 3, vv = tid & 7;   // (t, v) for the 16x8 scalar phases
    float qs = 0.f;
    if (tid < 128) {
      float t1 = vsx[b][tt][vv] -
                 ((pd[0][tt][vv] + pd[1][tt][vv]) + (pd[2][tt][vv] + pd[3][tt][vv]));
      qs = (qd[0][tt][vv] + qd[1][tt][vv]) + (qd[2][tt][vv] + qd[3][tt][vv]);
      t1r[tt][vv] = t1;
    }
    __syncthreads();  // B3
    if (tid < 128) {
      float u = 0.f;
#pragma unroll
      for (int s = 0; s < CC; ++s) u = fmaf(wsx[b][tt][s], t1r[s][vv], u);
      ufx[tt][vv] = u;
      u16 uh = f2bf(u);
      ush[vv][tt] = uh;
      usl[vv][tt] = f2bf(u - bflo(uh));
    }
    __syncthreads();  // B4
    if (tid < 128) {
      float o = qs;
#pragma unroll
      for (int s = 0; s < CC; ++s) o = fmaf(msx[b][tt][s], ufx[s][vv], o);
      yf[((size_t)bh * kT + ch * CC + tt) * kV + cb + vv] = o;
    }
    // state update: S = lam*S + Kbar^T U  (hi/lo mfma pair per tile)
    short8 bH = *(const short8*)&ush[m15][q8];
    short8 bL = *(const short8*)&usl[m15][q8];
#pragma unroll
    for (int j = 0; j < 2; ++j) {
      const int kt = w * 32 + j * 16;
      f32x4 S = St[j];
#pragma unroll
      for (int r = 0; r < 4; ++r) S[r] *= lamx[b][kt + q * 4 + r];
      short8 aB = *(const short8*)&kbs[b][kt + m15][q8];
      S = __builtin_amdgcn_mfma_f32_16x16x32_bf16(aB, bL, S, 0, 0, 0);
      S = __builtin_amdgcn_mfma_f32_16x16x32_bf16(aB, bH, S, 0, 0, 0);
      St[j] = S;
      u16 h0 = f2bf(S[0]), h1 = f2bf(S[1]), h2 = f2bf(S[2]), h3 = f2bf(S[3]);
      uint2 hw; hw.x = (u32)h0 | ((u32)h1 << 16); hw.y = (u32)h2 | ((u32)h3 << 16);
      *(uint2*)&s0h[m15][kt + q * 4] = hw;
      uint2 lw;
      lw.x = (u32)f2bf(S[0] - bflo(h0)) | ((u32)f2bf(S[1] - bflo(h1)) << 16);
      lw.y = (u32)f2bf(S[2] - bflo(h2)) | ((u32)f2bf(S[3] - bflo(h3)) << 16);
      *(uint2*)&s0l[m15][kt + q * 4] = lw;
    }
  }
}

// ---------------- rmsnorm * o_norm_w * sigmoid(gate+bg) -> bf16 -----------
__global__ __launch_bounds__(256) void postk(
    const float* __restrict__ yf, const u16* __restrict__ gateb,
    const float* __restrict__ bg, const float* __restrict__ onw,
    u16* __restrict__ ygb) {
  const int wid  = blockIdx.x * 4 + (threadIdx.x >> 6);
  const int lane = threadIdx.x & 63;
  const int h  = wid & 15;
  const int bt = wid >> 4;
  const int t  = bt & (kT - 1);
  const int b  = bt >> 11;
  const int v0 = lane * 2;
  const size_t yi = ((size_t)(b * kH + h) * kT + t) * kV + v0;
  float2 yv = *(const float2*)(yf + yi);
  float s = yv.x * yv.x + yv.y * yv.y;
#pragma unroll
  for (int m = 1; m < 64; m <<= 1) s += __shfl_xor(s, m);
  float scale = rsqrtf(s * (1.0f / 128.0f) + 1.1920929e-07f);
  const size_t gi = (size_t)bt * kHV + (size_t)h * kV + v0;
  u32 ug = *(const u32*)(gateb + gi);
  float g0 = bflo(ug) + bg[h * kV + v0];
  float g1 = bfhi(ug) + bg[h * kV + v0 + 1];
  float r0 = yv.x * scale * onw[v0] * sigmoidf(g0);
  float r1 = yv.y * scale * onw[v0 + 1] * sigmoidf(g1);
  *(u32*)(ygb + gi) = (u32)f2bf(r0) | ((u32)f2bf(r1) << 16);
}

// ---------------- host launcher ----------------
extern "C" void kernel_launch(void* const* d_in, const int* in_sizes, int n_in,
                              void* d_out, int out_size, void* d_ws, size_t ws_size,
                              hipStream_t stream) {
  (void)in_sizes; (void)n_in; (void)out_size; (void)ws_size;
  const float* x    = (const float*)d_in[0];
  const float* Wq   = (const float*)d_in[1];
  const float* Wk   = (const float*)d_in[2];
  const float* Wv   = (const float*)d_in[3];
  const float* Wf1  = (const float*)d_in[4];
  const float* Wf2  = (const float*)d_in[5];
  const float* Wb   = (const float*)d_in[6];
  const float* Wg1  = (const float*)d_in[7];
  const float* Wg2  = (const float*)d_in[8];
  const float* bg   = (const float*)d_in[9];
  const float* onw  = (const float*)d_in[10];
  const float* Wout = (const float*)d_in[11];
  const float* A_log   = (const float*)d_in[12];
  const float* dt_bias = (const float*)d_in[13];
  const float* qcw  = (const float*)d_in[14];
  const float* kcw  = (const float*)d_in[15];
  const float* vcw  = (const float*)d_in[16];

  char* ws = (char*)d_ws;
  u16* xb     = (u16*)(ws + OFF_XB);
  u16* wqkv   = (u16*)(ws + OFF_WQKV);
  u16* wf1b   = (u16*)(ws + OFF_WF1B);
  u16* wg1b   = (u16*)(ws + OFF_WG1B);
  u16* wbp    = (u16*)(ws + OFF_WBP);
  u16* wf2b   = (u16*)(ws + OFF_WF2B);
  u16* wg2b   = (u16*)(ws + OFF_WG2B);
  u16* woutb  = (u16*)(ws + OFF_WOUTB);
  u16* fgb    = (u16*)(ws + OFF_FGB);
  u16* qkvraw = (u16*)(ws + OFF_QKVR);
  u16* graw   = (u16*)(ws + OFF_GRAW);
  u16* gateb  = (u16*)(ws + OFF_GATEB);
  u16* qhb    = (u16*)(ws + OFF_QHB);
  u16* khb    = (u16*)(ws + OFF_KHB);
  u16* kbb    = (u16*)(ws + OFF_KBB);
  u16* ygb    = (u16*)(ws + OFF_YGB);
  float* qcf   = (float*)(ws + OFF_QC);
  float* kcf   = (float*)(ws + OFF_KC);
  float* vtf   = (float*)(ws + OFF_VT);
  float* gkf   = (float*)(ws + OFF_GK);
  float* betaf = (float*)(ws + OFF_BETA);
  float* yff   = (float*)(ws + OFF_YF);
  float* lamf  = (float*)(ws + OFF_LAM);
  float* winvf = (float*)(ws + OFF_WINV);
  float* mmf   = (float*)(ws + OFF_MM);

  cast_all<<<25600, 256, 0, stream>>>(x, Wq, Wk, Wv, Wout, Wf1, Wg1, Wf2, Wg2,
                                      xb, wqkv, woutb, wf1b, wg1b, wf2b, wg2b);
  pad_wb<<<(128 * 2048 / 4 + 255) / 256, 256, 0, stream>>>(Wb, wbp);

  dim3 blk(256);
  // qkv: [4096,6144] = x @ [Wq;Wk;Wv]^T
  gemm_bt<true><<<dim3(kM / 128, 6144 / 128), blk, 0, stream>>>(
      xb, wqkv, qkvraw, kD, kD, 6144, kD);
  // fgb: [4096,384] = x @ [Wf1;Wg1;Wbp]^T
  gemm_bt<true><<<dim3(kM / 128, 384 / 128), blk, 0, stream>>>(
      xb, wf1b, fgb, kD, kD, 384, kD);
  // graw: [4096,2048] = f1 @ Wf2^T   (A = fgb cols 0..127, lda 384)
  gemm_bt<true><<<dim3(kM / 128, kHK / 128), blk, 0, stream>>>(
      fgb, wf2b, graw, 384, kV, kHK, kV);
  // gateb: [4096,2048] = g1 @ Wg2^T  (A = fgb cols 128..255)
  gemm_bt<true><<<dim3(kM / 128, kHV / 128), blk, 0, stream>>>(
      fgb + 128, wg2b, gateb, 384, kV, kHV, kV);

  convprep<<<kB * kT * kH / 8, 256, 0, stream>>>(qkvraw, graw, fgb,
                                                 qcw, kcw, vcw, A_log, dt_bias,
                                                 qcf, kcf, vtf, gkf, betaf);

  kda_p1<<<32 * NCH, 256, 0, stream>>>(qcf, kcf, gkf, betaf,
                                       qhb, khb, kbb, lamf, winvf, mmf);
  kda_p2<<<512, 256, 0, stream>>>(khb, qhb, kbb, lamf, winvf, mmf, vtf, yff);

  postk<<<kB * kT * kH / 4, 256, 0, stream>>>(yff, gateb, bg, onw, ygb);

  // out: [4096,2048] = yg @ Wout^T
  gemm_bt<false><<<dim3(kM / 128, kD / 128), blk, 0, stream>>>(
      ygb, woutb, (float*)d_out, kHV, kHV, kD, kHV);
}